// Round 4
// baseline (270.759 us; speedup 1.0000x reference)
//
#include <hip/hip_runtime.h>
#include <hip/hip_bf16.h>

#define EMBED 1024
#define HEADS 16
#define HD    64
#define NB    4
#define SEQ   2048

typedef __bf16 bf16x2 __attribute__((ext_vector_type(2)));
typedef __bf16 bf16x8 __attribute__((ext_vector_type(8)));
typedef float  f32x4  __attribute__((ext_vector_type(4)));
typedef float  f32x16 __attribute__((ext_vector_type(16)));
typedef unsigned uint2v __attribute__((ext_vector_type(2)));

__device__ __forceinline__ unsigned short f2bf(float f) {
    union { float f; unsigned u; } v; v.f = f;
    unsigned r = v.u + 0x7fffu + ((v.u >> 16) & 1u);   // RNE, inputs finite
    return (unsigned short)(r >> 16);
}
// packed 2xf32 -> bf16x2 (low=a, high=b)
__device__ __forceinline__ unsigned pack2(float a, float b) {
#if __has_builtin(__builtin_amdgcn_cvt_pk_bf16_f32)
    union { bf16x2 v; unsigned u; } c;
    c.v = __builtin_amdgcn_cvt_pk_bf16_f32(a, b);
    return c.u;
#else
    return (unsigned)f2bf(a) | ((unsigned)f2bf(b) << 16);
#endif
}

// LDS-only barrier: waits ds-ops, does NOT drain vmcnt (unlike __syncthreads),
// so prefetch global loads stay in flight across the barrier (T4).
__device__ __forceinline__ void sync_lds() {
    asm volatile("s_waitcnt lgkmcnt(0)" ::: "memory");
    __builtin_amdgcn_s_barrier();
    asm volatile("" ::: "memory");
}

// ---------------------------------------------------------------- Wo -> bf16
__global__ __launch_bounds__(256) void cvt_kernel(const float* __restrict__ src,
                                                  unsigned* __restrict__ dst) {
    int i = blockIdx.x * 256 + threadIdx.x;
    float4 v = ((const float4*)src)[i];
    uint2 o;
    o.x = pack2(v.x, v.y);
    o.y = pack2(v.z, v.w);
    ((uint2*)dst)[i] = o;
}

// ------------------------------------------------------- Q/K/V projections
// 256 s-rows per block. p=0: query@Wq^T (scale log2(e)/32 folded) -> Qp [h][s][d]
// p=1: keys@Wk^T -> Kp [h][s][d]   p=2: values@Wv^T -> Vt [h][d][s]
__global__ __launch_bounds__(256) void proj_kernel(
    const float* __restrict__ xq, const float* __restrict__ xk, const float* __restrict__ xv,
    const float* __restrict__ Wq, const float* __restrict__ Wk, const float* __restrict__ Wv,
    unsigned short* __restrict__ Qp, unsigned short* __restrict__ Kp, unsigned short* __restrict__ Vt)
{
    __shared__ __align__(16) unsigned short Wl[64 * 72];
    __shared__ __align__(16) unsigned short Xl[256 * 72];

    int bx = blockIdx.x;                  // 1536 = 3 * 512
    int p  = bx >> 9;
    int r  = bx & 511;
    int st = r & 7, h = (r >> 3) & 15, n = r >> 7;
    int s0 = st * 256;

    const float* x = (p == 0) ? xq : (p == 1) ? xk : xv;
    const float* W = (p == 0) ? Wq : (p == 1) ? Wk : Wv;
    const float sc = (p == 0) ? 0.045084220027780106f : 1.0f;  // log2(e)/32

    int tid = threadIdx.x;

    for (int i = 0; i < 4; ++i) {
        int idx = tid + i * 256;
        int row = idx >> 4, c4 = idx & 15;
        float4 wv = ((const float4*)W)[row * 16 + c4];
        uint2 pw;
        pw.x = pack2(wv.x, wv.y);
        pw.y = pack2(wv.z, wv.w);
        *(uint2*)&Wl[row * 72 + c4 * 4] = pw;
    }
    const float* xbase = x + (size_t)(n * SEQ + s0) * EMBED + h * HD;
    for (int i = 0; i < 16; ++i) {
        int idx = tid + i * 256;
        int row = idx >> 4, c4 = idx & 15;
        float4 v = *(const float4*)(xbase + (size_t)row * EMBED + c4 * 4);
        uint2 px;
        px.x = pack2(v.x, v.y);
        px.y = pack2(v.z, v.w);
        *(uint2*)&Xl[row * 72 + c4 * 4] = px;
    }
    __syncthreads();

    int w = tid >> 6, lane = tid & 63, ln = lane & 15, qd = lane >> 4;

    bf16x8 a[4][2], b[4][2];
#pragma unroll
    for (int mt = 0; mt < 4; ++mt)
#pragma unroll
        for (int kt = 0; kt < 2; ++kt)
            a[mt][kt] = *(const bf16x8*)&Xl[(w * 64 + mt * 16 + ln) * 72 + kt * 32 + qd * 8];
#pragma unroll
    for (int i = 0; i < 4; ++i)
#pragma unroll
        for (int kt = 0; kt < 2; ++kt)
            b[i][kt] = *(const bf16x8*)&Wl[(i * 16 + ln) * 72 + kt * 32 + qd * 8];

    f32x4 acc[4][4];
    const f32x4 fz = {0.f, 0.f, 0.f, 0.f};
#pragma unroll
    for (int i = 0; i < 4; ++i)
#pragma unroll
        for (int j = 0; j < 4; ++j) acc[i][j] = fz;

    if (p < 2) {
#pragma unroll
        for (int i = 0; i < 4; ++i)
#pragma unroll
            for (int j = 0; j < 4; ++j) {
                acc[i][j] = __builtin_amdgcn_mfma_f32_16x16x32_bf16(b[i][0], a[j][0], acc[i][j], 0, 0, 0);
                acc[i][j] = __builtin_amdgcn_mfma_f32_16x16x32_bf16(b[i][1], a[j][1], acc[i][j], 0, 0, 0);
            }
#pragma unroll
        for (int i = 0; i < 4; ++i)
#pragma unroll
            for (int j = 0; j < 4; ++j) {
                uint2 pk;
                pk.x = pack2(acc[i][j][0] * sc, acc[i][j][1] * sc);
                pk.y = pack2(acc[i][j][2] * sc, acc[i][j][3] * sc);
                *(uint2*)&Xl[(w * 64 + j * 16 + ln) * 72 + i * 16 + qd * 4] = pk;
            }
        __syncthreads();
        unsigned short* outp = (p == 0 ? Qp : Kp) + (size_t)(n * HEADS + h) * SEQ * HD + (size_t)s0 * HD;
        for (int i = 0; i < 8; ++i) {
            int idx = tid + i * 256;
            int row = idx >> 3, ch = idx & 7;
            *(uint4*)(outp + (size_t)row * HD + ch * 8) = *(const uint4*)&Xl[row * 72 + ch * 8];
        }
    } else {
#pragma unroll
        for (int mt = 0; mt < 4; ++mt)
#pragma unroll
            for (int i = 0; i < 4; ++i) {
                acc[mt][i] = __builtin_amdgcn_mfma_f32_16x16x32_bf16(a[mt][0], b[i][0], acc[mt][i], 0, 0, 0);
                acc[mt][i] = __builtin_amdgcn_mfma_f32_16x16x32_bf16(a[mt][1], b[i][1], acc[mt][i], 0, 0, 0);
            }
        __syncthreads();
#pragma unroll
        for (int mt = 0; mt < 4; ++mt)
#pragma unroll
            for (int i = 0; i < 4; ++i) {
                uint2 pk;
                pk.x = pack2(acc[mt][i][0], acc[mt][i][1]);
                pk.y = pack2(acc[mt][i][2], acc[mt][i][3]);
                *(uint2*)&Xl[(i * 16 + ln) * 264 + w * 64 + mt * 16 + qd * 4] = pk;
            }
        __syncthreads();
        unsigned short* outp = Vt + (size_t)(n * HEADS + h) * HD * SEQ + s0;
        for (int i = 0; i < 8; ++i) {
            int idx = tid + i * 256;
            int row = idx >> 5, ch = idx & 31;
            *(uint4*)(outp + (size_t)row * SEQ + ch * 8) = *(const uint4*)&Xl[row * 264 + ch * 8];
        }
    }
}

// ------------------------------------------------------------ flash attention
// 32x32x16 MFMAs. S^T = K Q^T (C: col=q, row=key). P stays in registers.
// T15 software pipeline: per iteration  QK^T(i) [MFMA] -> PV(i-1) with prev
// pkP [MFMA, independent of QK(i)] -> stage/loads -> softmax(i) [VALU].
// Triple-buffered LDS (3 x 18.4 KB); in-loop barriers are lgkmcnt-only
// (sync_lds) so prefetch global loads stay in flight across barriers (T4).
__global__ __launch_bounds__(512, 4) void attn_kernel(
    const unsigned short* __restrict__ Qp, const unsigned short* __restrict__ Kp,
    const unsigned short* __restrict__ Vt, unsigned short* __restrict__ Xattn)
{
    __shared__ __align__(16) unsigned short SMEM[27648];   // 55,296 B = 3 x (K 4608 + V 4608)

    int bx = blockIdx.x;                 // 512 blocks: head*8 + qtile
    int head = bx >> 3, qt = bx & 7;
    int n = head >> 4, h16 = head & 15;
    int q0 = qt * 256;

    int tid = threadIdx.x;
    int w = tid >> 6, lane = tid & 63;
    int qc = lane & 31, hh = lane >> 5;

    const unsigned short* Qb = Qp + (size_t)head * SEQ * HD;
    const unsigned short* Kb = Kp + (size_t)head * SEQ * HD;
    const unsigned short* Vb = Vt + (size_t)head * HD * SEQ;

    // Q as B-operand (32x32x16): lane n=q, k(d) = kk*16 + hh*8 + j
    bf16x8 qb[4];
    {
        int qrow = q0 + w * 32 + qc;
#pragma unroll
        for (int kk = 0; kk < 4; ++kk)
            qb[kk] = *(const bf16x8*)(Qb + (size_t)qrow * HD + kk * 16 + hh * 8);
    }

    f32x16 ot0, ot1;
#pragma unroll
    for (int i = 0; i < 16; ++i) { ot0[i] = 0.f; ot1[i] = 0.f; }
    float ls[4] = {0.f, 0.f, 0.f, 0.f};     // 4-way partials, independent chains

    int srow = tid >> 3, sch = tid & 7;      // staging: 64 rows x 8 chunks
    int soff = srow * 72 + sch * 8;

    unsigned pkP[16];                        // P(prev chunk) packed bf16 pairs
    f32x16 c0, c1;                           // S^T accumulators (current chunk)

// ---- phase macros (static indices everywhere) ----
#define QK_STEP(KBASE)  do {                                                    \
    _Pragma("unroll")                                                           \
    for (int _i = 0; _i < 16; ++_i) { c0[_i] = 0.f; c1[_i] = 0.f; }             \
    __builtin_amdgcn_s_setprio(1);                                              \
    _Pragma("unroll")                                                           \
    for (int kk = 0; kk < 4; ++kk) {                                            \
        bf16x8 ka = *(const bf16x8*)&SMEM[(KBASE) + qc * 72 + kk * 16 + hh * 8];\
        c0 = __builtin_amdgcn_mfma_f32_32x32x16_bf16(ka, qb[kk], c0, 0, 0, 0);  \
    }                                                                           \
    _Pragma("unroll")                                                           \
    for (int kk = 0; kk < 4; ++kk) {                                            \
        bf16x8 ka = *(const bf16x8*)&SMEM[(KBASE) + (32 + qc) * 72 + kk * 16 + hh * 8]; \
        c1 = __builtin_amdgcn_mfma_f32_32x32x16_bf16(ka, qb[kk], c1, 0, 0, 0);  \
    }                                                                           \
    __builtin_amdgcn_s_setprio(0);                                              \
} while (0)

#define SOFTMAX_STEP() do {                                                     \
    _Pragma("unroll")                                                           \
    for (int _i = 0; _i < 8; ++_i) {                                            \
        float p0 = __builtin_amdgcn_exp2f(c0[2 * _i]);                          \
        float p1 = __builtin_amdgcn_exp2f(c0[2 * _i + 1]);                      \
        ls[_i & 3] += p0 + p1;                                                  \
        pkP[_i] = pack2(p0, p1);                                                \
    }                                                                           \
    _Pragma("unroll")                                                           \
    for (int _i = 0; _i < 8; ++_i) {                                            \
        float p0 = __builtin_amdgcn_exp2f(c1[2 * _i]);                          \
        float p1 = __builtin_amdgcn_exp2f(c1[2 * _i + 1]);                      \
        ls[_i & 3] += p0 + p1;                                                  \
        pkP[8 + _i] = pack2(p0, p1);                                            \
    }                                                                           \
} while (0)

#if __has_builtin(__builtin_amdgcn_permlane32_swap)
#define PV_FRAG(P, BASE, BB) do {                                               \
    uint2v r  = __builtin_amdgcn_permlane32_swap((P)[(BASE) + 0], (P)[(BASE) + 2], false, false); \
    uint2v rr = __builtin_amdgcn_permlane32_swap((P)[(BASE) + 1], (P)[(BASE) + 3], false, false); \
    BB.u[0] = r.x; BB.u[1] = rr.x; BB.u[2] = r.y; BB.u[3] = rr.y;               \
} while (0)
#else
#define PV_FRAG(P, BASE, BB) do {                                               \
    unsigned s0_ = hh ? (P)[(BASE) + 0] : (P)[(BASE) + 2];                      \
    unsigned s1_ = hh ? (P)[(BASE) + 1] : (P)[(BASE) + 3];                      \
    unsigned r0_ = (unsigned)__shfl_xor((int)s0_, 32);                          \
    unsigned r1_ = (unsigned)__shfl_xor((int)s1_, 32);                          \
    BB.u[0] = hh ? r0_ : (P)[(BASE) + 0];                                       \
    BB.u[1] = hh ? r1_ : (P)[(BASE) + 1];                                       \
    BB.u[2] = hh ? (P)[(BASE) + 2] : r0_;                                       \
    BB.u[3] = hh ? (P)[(BASE) + 3] : r1_;                                       \
} while (0)
#endif

#define PV_STEP(VBASE) do {                                                     \
    __builtin_amdgcn_s_setprio(1);                                              \
    _Pragma("unroll")                                                           \
    for (int g = 0; g < 4; ++g) {                                               \
        union { unsigned u[4]; bf16x8 v; } bb;                                  \
        PV_FRAG(pkP, (g >> 1) * 8 + (g & 1) * 4, bb);                           \
        bf16x8 va0 = *(const bf16x8*)&SMEM[(VBASE) + qc * 72 + g * 16 + hh * 8];        \
        bf16x8 va1 = *(const bf16x8*)&SMEM[(VBASE) + (32 + qc) * 72 + g * 16 + hh * 8]; \
        ot0 = __builtin_amdgcn_mfma_f32_32x32x16_bf16(va0, bb.v, ot0, 0, 0, 0); \
        ot1 = __builtin_amdgcn_mfma_f32_32x32x16_bf16(va1, bb.v, ot1, 0, 0, 0); \
    }                                                                           \
    __builtin_amdgcn_s_setprio(0);                                              \
} while (0)

    // ---- prologue: chunk0 direct to buf0; chunk1 into regs
    uint4 rK, rV;
    rK = *(const uint4*)(Kb + (size_t)srow * HD + sch * 8);
    rV = *(const uint4*)(Vb + (size_t)srow * SEQ + 0 + sch * 8);
    *(uint4*)&SMEM[0 + soff] = rK;          // K buf0
    *(uint4*)&SMEM[4608 + soff] = rV;       // V buf0
    rK = *(const uint4*)(Kb + (size_t)(64 + srow) * HD + sch * 8);
    rV = *(const uint4*)(Vb + (size_t)srow * SEQ + 64 + sch * 8);

    sync_lds();                              // buf0 visible
    QK_STEP(0);                              // chunk 0
    *(uint4*)&SMEM[9216 + soff] = rK;        // stage chunk1 -> buf1 (unread yet, no race)
    *(uint4*)&SMEM[9216 + 4608 + soff] = rV;
    rK = *(const uint4*)(Kb + (size_t)(128 + srow) * HD + sch * 8);   // chunk2
    rV = *(const uint4*)(Vb + (size_t)srow * SEQ + 128 + sch * 8);
    SOFTMAX_STEP();                          // pkP = P(chunk0)

    int b_prv = 0, b_cur = 9216, b_nxt = 18432;

    for (int i = 1; i < 32; ++i) {
        sync_lds();                          // buf[cur] visible; reads of buf[nxt] (chunk i-2) done
        QK_STEP(b_cur);                      // chunk i (MFMA)
        if (i < 31) {                        // stage chunk i+1 (regs loaded last iter)
            *(uint4*)&SMEM[b_nxt + soff] = rK;
            *(uint4*)&SMEM[b_nxt + 4608 + soff] = rV;
        }
        PV_STEP(b_prv + 4608);               // chunk i-1 (MFMA, uses prev pkP)
        if (i < 30) {                        // issue loads chunk i+2 (fly across barriers)
            int kn = (i + 2) * 64;
            rK = *(const uint4*)(Kb + (size_t)(kn + srow) * HD + sch * 8);
            rV = *(const uint4*)(Vb + (size_t)srow * SEQ + kn + sch * 8);
        }
        SOFTMAX_STEP();                      // pkP = P(chunk i)  (VALU, overlaps MFMAs above)
        int t = b_prv; b_prv = b_cur; b_cur = b_nxt; b_nxt = t;
    }
    PV_STEP(b_prv + 4608);                   // final PV: chunk 31

#undef QK_STEP
#undef SOFTMAX_STEP
#undef PV_FRAG
#undef PV_STEP

    // ---- finish l (combine partials, then the xor-32 partner half)
    float lsum = (ls[0] + ls[1]) + (ls[2] + ls[3]);
    lsum += __shfl_xor(lsum, 32);
    float inv = 1.0f / lsum;

    // ---- stage O [q][d] into SMEM (reuses K/V space), coalesced store
    __syncthreads();
    int qlocal = w * 32 + qc;
#pragma unroll
    for (int dt = 0; dt < 2; ++dt) {
        const f32x16& o = dt ? ot1 : ot0;
#pragma unroll
        for (int g = 0; g < 4; ++g) {
            uint2 p;
            p.x = pack2(o[4 * g + 0] * inv, o[4 * g + 1] * inv);
            p.y = pack2(o[4 * g + 2] * inv, o[4 * g + 3] * inv);
            *(uint2*)&SMEM[qlocal * 72 + dt * 32 + g * 8 + hh * 4] = p;
        }
    }
    __syncthreads();
    unsigned short* ob = Xattn + (size_t)(n * SEQ + q0) * EMBED + h16 * HD;
#pragma unroll
    for (int i = 0; i < 4; ++i) {
        int idx = tid + i * 512;                 // 256 rows x 8 chunks
        int row = idx >> 3, ch = idx & 7;
        *(uint4*)(ob + (size_t)row * EMBED + ch * 8) = *(const uint4*)&SMEM[row * 72 + ch * 8];
    }
}

// ----------------------------------------------------- out = Xattn@Wo^T + bo
// 64x128 tiles -> grid 1024 -> 4 blocks/CU (16 waves/CU): cross-block TLP
// hides the synchronous K-loop's staging latency. LDS 27.6 KB.
__global__ __launch_bounds__(256, 4) void outproj_kernel(
    const unsigned short* __restrict__ X, const unsigned short* __restrict__ Wb,
    const float* __restrict__ bo, float* __restrict__ out)
{
    __shared__ __align__(16) unsigned short Al[64 * 72];
    __shared__ __align__(16) unsigned short Bl[128 * 72];

    int bx = blockIdx.x;                 // 1024 = 128 row-tiles x 8 col-tiles
    int cm = bx >> 3, cn = bx & 7;
    int m0 = cm * 64, c0 = cn * 128;
    int tid = threadIdx.x;
    int w = tid >> 6, lane = tid & 63, ln = lane & 15, qd = lane >> 4;
    int chw = w * 32;                    // wave's 32-col slice

    f32x4 acc[4][2];
    const f32x4 fz = {0.f, 0.f, 0.f, 0.f};
#pragma unroll
    for (int mt = 0; mt < 4; ++mt)
#pragma unroll
        for (int nt = 0; nt < 2; ++nt) acc[mt][nt] = fz;

    for (int k0 = 0; k0 < EMBED; k0 += 64) {
        {
#pragma unroll
            for (int i = 0; i < 2; ++i) {
                int idx = tid + i * 256;          // 512 uint4
                int r2 = idx >> 3, c2 = idx & 7;
                uint4 av = *(const uint4*)(X + (size_t)(m0 + r2) * EMBED + k0 + c2 * 8);
                *(uint4*)&Al[r2 * 72 + c2 * 8] = av;
            }
#pragma unroll
            for (int i = 0; i < 4; ++i) {
                int idx = tid + i * 256;          // 1024 uint4
                int r2 = idx >> 3, c2 = idx & 7;
                uint4 bv = *(const uint4*)(Wb + (size_t)(c0 + r2) * EMBED + k0 + c2 * 8);
                *(uint4*)&Bl[r2 * 72 + c2 * 8] = bv;
            }
        }
        __syncthreads();
        bf16x8 af[4][2], bf_[2][2];
#pragma unroll
        for (int mt = 0; mt < 4; ++mt)
#pragma unroll
            for (int kt = 0; kt < 2; ++kt)
                af[mt][kt] = *(const bf16x8*)&Al[(mt * 16 + ln) * 72 + kt * 32 + qd * 8];
#pragma unroll
        for (int nt = 0; nt < 2; ++nt)
#pragma unroll
            for (int kt = 0; kt < 2; ++kt)
                bf_[nt][kt] = *(const bf16x8*)&Bl[(chw + nt * 16 + ln) * 72 + kt * 32 + qd * 8];
#pragma unroll
        for (int mt = 0; mt < 4; ++mt)
#pragma unroll
            for (int nt = 0; nt < 2; ++nt) {
                acc[mt][nt] = __builtin_amdgcn_mfma_f32_16x16x32_bf16(af[mt][0], bf_[nt][0], acc[mt][nt], 0, 0, 0);
                acc[mt][nt] = __builtin_amdgcn_mfma_f32_16x16x32_bf16(af[mt][1], bf_[nt][1], acc[mt][nt], 0, 0, 0);
            }
        __syncthreads();
    }

#pragma unroll
    for (int nt = 0; nt < 2; ++nt) {
        int col = c0 + chw + nt * 16 + ln;
        float bias = bo[col];
#pragma unroll
        for (int mt = 0; mt < 4; ++mt) {
            int row = m0 + mt * 16 + qd * 4;
#pragma unroll
            for (int rg = 0; rg < 4; ++rg)
                out[(size_t)(row + rg) * EMBED + col] = acc[mt][nt][rg] + bias;
        }
    }
}

// --------------------------------------------------------------------- launch
extern "C" void kernel_launch(void* const* d_in, const int* in_sizes, int n_in,
                              void* d_out, int out_size, void* d_ws, size_t ws_size,
                              hipStream_t stream) {
    const float* values = (const float*)d_in[0];
    const float* keys   = (const float*)d_in[1];
    const float* query  = (const float*)d_in[2];
    const float* Wv     = (const float*)d_in[3];
    const float* Wk     = (const float*)d_in[4];
    const float* Wq     = (const float*)d_in[5];
    const float* Wo     = (const float*)d_in[6];
    const float* bo     = (const float*)d_in[7];
    float* out = (float*)d_out;

    unsigned short* ws = (unsigned short*)d_ws;
    const size_t HSZ = (size_t)NB * HEADS * SEQ * HD;   // 8388608 elems
    unsigned short* Qp = ws;
    unsigned short* Kp = Qp + HSZ;
    unsigned short* Vt = Kp + HSZ;
    unsigned short* Xa = Vt + HSZ;
    unsigned short* Wb = Xa + HSZ;                       // 1024*1024 elems

    cvt_kernel<<<1024, 256, 0, stream>>>(Wo, (unsigned*)Wb);
    proj_kernel<<<1536, 256, 0, stream>>>(query, keys, values, Wq, Wk, Wv, Qp, Kp, Vt);
    attn_kernel<<<512, 512, 0, stream>>>(Qp, Kp, Vt, Xa);
    outproj_kernel<<<1024, 256, 0, stream>>>(Xa, Wb, bo, out);
}